// Round 6
// baseline (962.798 us; speedup 1.0000x reference)
//
#include <hip/hip_runtime.h>

// TemporalLayer: T=64, N=2048, D=512, weight=0.5, causal attention, no sqrt(d) scale.
// fp16 MFMA (v_mfma_f32_16x16x32_f16, fp32 accum) internally; fp32 in/out.
//
// R6 changes vs R5 (953us; attn 378us: MfmaUtil 25%, VALU 12%, HBM 10%, VGPR 92):
//  Theory: loops are L2-latency-bound; compiler only pipelines ~1 iter (92 VGPR).
//  1. Explicit register prefetch in all MFMA loops, fully unrolled with NAMED
//     rotating buffers (compile-time indices, no scratch): weights 2-deep
//     (3 buffers, ~500cyc cover), LDS t-fragments 1-deep (2 buffers).
//     attn __launch_bounds__(512,2): VGPR cap 256 (occupancy already 1 blk/CU).
//  2. ff_final: 1-deep weight prefetch, __launch_bounds__(512,4) to guarantee
//     2 blocks/CU (VGPR<=128); 4 waves/SIMD hide the LDS reads.
//  3. Middle-section barriers -> raw lgkmcnt(0)+s_barrier (LDS-only ordering;
//     globals stay in flight across them).
// fp16 out-scratch still lives in the UPPER HALF of each node's fp32 out slot.

#define TT 64
#define NN 2048
#define DD 512

typedef _Float16 f16x8 __attribute__((ext_vector_type(8)));
typedef float    f32x4 __attribute__((ext_vector_type(4)));

#define MFMA16(a,b,c) __builtin_amdgcn_mfma_f32_16x16x32_f16((a),(b),(c),0,0,0)

#define RAW_BARRIER() do { \
    asm volatile("s_waitcnt lgkmcnt(0)" ::: "memory"); \
    __builtin_amdgcn_s_barrier(); \
    __builtin_amdgcn_sched_barrier(0); \
  } while (0)

// 4 weight fragments (one kb, 4 row-tiles 8192 halfs apart) from L2.
#define LDW4(W, F, KB) do { \
    W[0] = *(const f16x8*)((F) + (size_t)(KB) * 512); \
    W[1] = *(const f16x8*)((F) + (size_t)(KB) * 512 + 8192); \
    W[2] = *(const f16x8*)((F) + (size_t)(KB) * 512 + 16384); \
    W[3] = *(const f16x8*)((F) + (size_t)(KB) * 512 + 24576); \
  } while (0)

// 4 t-tile fragments (rows 16*rt + l15) from swizzled LDS.
#define LDA4(A, BASE, KB) do { \
    A[0] = *(const f16x8*)((BASE) + (l15) * 1024 + ((((KB) * 64) + quad * 16) ^ rswz)); \
    A[1] = *(const f16x8*)((BASE) + (16 + l15) * 1024 + ((((KB) * 64) + quad * 16) ^ rswz)); \
    A[2] = *(const f16x8*)((BASE) + (32 + l15) * 1024 + ((((KB) * 64) + quad * 16) ^ rswz)); \
    A[3] = *(const f16x8*)((BASE) + (48 + l15) * 1024 + ((((KB) * 64) + quad * 16) ^ rswz)); \
  } while (0)

// One kb step: 16 MFMAs on current buffers, then refill (weights kb+3, lds kb+2).
#define PRJ_STEP(WC, AC, ACC, F, BASE, KB) do { \
    _Pragma("unroll") \
    for (int rt_ = 0; rt_ < 4; ++rt_) { \
      _Pragma("unroll") \
      for (int ct_ = 0; ct_ < 4; ++ct_) \
        ACC[rt_][ct_] = MFMA16(AC[rt_], WC[ct_], ACC[rt_][ct_]); \
    } \
    if ((KB) + 3 < 16) LDW4(WC, F, (KB) + 3); \
    if ((KB) + 2 < 16) LDA4(AC, BASE, (KB) + 2); \
  } while (0)

// Full 16-kb projection with 2-deep weight / 1-deep lds register pipeline.
#define PROJ16(F, BASE, ACC) do { \
    f16x8 wA_[4], wB_[4], wC_[4], aA_[4], aB_[4]; \
    LDW4(wA_, F, 0); LDW4(wB_, F, 1); LDW4(wC_, F, 2); \
    LDA4(aA_, BASE, 0); LDA4(aB_, BASE, 1); \
    PRJ_STEP(wA_, aA_, ACC, F, BASE, 0); \
    PRJ_STEP(wB_, aB_, ACC, F, BASE, 1); \
    PRJ_STEP(wC_, aA_, ACC, F, BASE, 2); \
    PRJ_STEP(wA_, aB_, ACC, F, BASE, 3); \
    PRJ_STEP(wB_, aA_, ACC, F, BASE, 4); \
    PRJ_STEP(wC_, aB_, ACC, F, BASE, 5); \
    PRJ_STEP(wA_, aA_, ACC, F, BASE, 6); \
    PRJ_STEP(wB_, aB_, ACC, F, BASE, 7); \
    PRJ_STEP(wC_, aA_, ACC, F, BASE, 8); \
    PRJ_STEP(wA_, aB_, ACC, F, BASE, 9); \
    PRJ_STEP(wB_, aA_, ACC, F, BASE, 10); \
    PRJ_STEP(wC_, aB_, ACC, F, BASE, 11); \
    PRJ_STEP(wA_, aA_, ACC, F, BASE, 12); \
    PRJ_STEP(wB_, aB_, ACC, F, BASE, 13); \
    PRJ_STEP(wC_, aA_, ACC, F, BASE, 14); \
    PRJ_STEP(wA_, aB_, ACC, F, BASE, 15); \
  } while (0)

// ---- weights -> fp16 fragment-major ----
// tile(e,d) = (e>>4)*16 + (d>>5); lane = ((d>>3)&3)*16 + (e&15); half j = d&7.
// mats: 0=Wq^T 1=Wk^T 2=Wv^T (src [d][e], transposed) 3=lin_w (src [e][d]).
__global__ __launch_bounds__(256) void prep_weights(
    const float* __restrict__ Wq, const float* __restrict__ Wk,
    const float* __restrict__ Wv, const float* __restrict__ lw,
    _Float16* __restrict__ out)
{
  int gid = blockIdx.x * 256 + threadIdx.x;   // 131072 threads, 8 halfs each
  int mat = gid >> 15;
  int r   = gid & 32767;
  int tile = r >> 6;          // 0..511
  int l    = r & 63;          // lane slot
  int rowblk = tile >> 4;     // e block
  int kbb    = tile & 15;     // d block
  int e  = rowblk * 16 + (l & 15);
  int d0 = kbb * 32 + (l >> 4) * 8;
  union { _Float16 h[8]; uint4 u; } o;
  if (mat < 3) {
    const float* W = (mat == 0) ? Wq : (mat == 1) ? Wk : Wv;
    #pragma unroll
    for (int j = 0; j < 8; ++j)
      o.h[j] = (_Float16)W[(size_t)(d0 + j) * DD + e];   // transpose
  } else {
    #pragma unroll
    for (int j = 0; j < 8; ++j)
      o.h[j] = (_Float16)lw[(size_t)e * DD + d0 + j];
  }
  *(uint4*)(out + (size_t)gid * 8) = o.u;
}

// ---- fused per-node: temporal -> q,k -> scores -> softmax -> v -> out=attn@v ----
// grid = 2048 nodes, block = 512 (8 waves). LDS 109568 B (1 block/CU).
__global__ __launch_bounds__(512, 2) void attn_fused(
    const float* __restrict__ x, const float* __restrict__ pos,
    const _Float16* __restrict__ WF, _Float16* __restrict__ outp)
{
  __shared__ char smem[109568];
  char* const tstp = smem;            // [64] rows x 1024 B, XOR-swizzled temporal
  char* const qdp  = smem + 65536;    // [64][136] f16 stride 272 (q dump) -- aliased:
  char* const scb  = smem + 65536;    //   [64][68] f32 stride 272 (scores)
  char* const vdp  = smem + 65536;    //   8 x [32][68] f16 stride 136 (vT dump)
  char* const kdp  = smem + 82944;    // [64][136] f16 stride 272 (k dump)
  char* const atn  = smem + 100352;   // [64][72] f16 stride 144 (attn probs)

  const int n    = blockIdx.x;
  const int tid  = threadIdx.x;
  const int wid  = tid >> 6;
  const int lane = tid & 63;
  const int quad = lane >> 4;
  const int l15  = lane & 15;
  const size_t scrbase = (size_t)n * 65536 + 32768;   // fp16 scratch (halfs)

  const _Float16* const Fq = WF;
  const _Float16* const Fk = WF + 262144;
  const _Float16* const Fv = WF + 524288;

  // ---- stage temporal ONCE: row = tid>>3 (64 rows), 8 threads/row ----
  {
    const int row = tid >> 3, si = tid & 7;
    const float* xr = x + ((size_t)row * NN + n) * DD;
    const float* pr = pos + (size_t)row * DD;
    char* const dst = tstp + row * 1024;
    const int swz = (row & 7) << 4;
    #pragma unroll
    for (int kb = 0; kb < 16; ++kb) {
      f32x4 xv = *(const f32x4*)(xr + kb * 32 + 4 * si);
      f32x4 pv = *(const f32x4*)(pr + kb * 32 + 4 * si);
      union { _Float16 h[4]; unsigned long long u; } o;
      #pragma unroll
      for (int j = 0; j < 4; ++j) o.h[j] = (_Float16)(xv[j] + pv[j]);
      *(unsigned long long*)(dst + ((kb * 64 + si * 8) ^ swz)) = o.u;
    }
  }
  RAW_BARRIER();

  const int rswz = (l15 & 7) << 4;   // row&7 == l15&7 for rows 16*rt + l15
  f32x4 sacc[2] = {};   // this wave's 2 score tiles, accumulated over all 512 e

  for (int ph = 0; ph < 2; ++ph) {          // e in [ph*256, ph*256+256)
    f32x4 acc[4][4] = {};                   // q- or k-slice [64 t][64 e] of this wave
    const bool isK = (wid >= 4);
    const int  esl = wid & 3;
    const _Float16* const fwave =
        (isK ? Fk : Fq) + (size_t)(ph * 16 + esl * 4) * 8192 + (size_t)lane * 8;

    PROJ16(fwave, tstp, acc);               // zero barriers; reg-pipelined

    // dump 128-col blocks of q,k -> LDS, accumulate scores += q_c @ k_c^T
    for (int r = 0; r < 2; ++r) {
      RAW_BARRIER();
      if ((esl >> 1) == r) {
        char* dst = isK ? kdp : qdp;
        const int colbase = (esl & 1) * 64;
        #pragma unroll
        for (int rt = 0; rt < 4; ++rt)
          #pragma unroll
          for (int ct = 0; ct < 4; ++ct)
            #pragma unroll
            for (int rg = 0; rg < 4; ++rg)
              *(_Float16*)(dst + (16*rt + quad*4 + rg)*272 + (colbase + 16*ct + l15)*2)
                  = (_Float16)acc[rt][ct][rg];
      }
      RAW_BARRIER();
      const int srt = wid >> 1, sct0 = (wid & 1) * 2;
      #pragma unroll
      for (int ks = 0; ks < 4; ++ks) {
        f16x8 aq = *(const f16x8*)(qdp + (16*srt + l15)*272 + ks*64 + quad*16);
        #pragma unroll
        for (int j = 0; j < 2; ++j) {
          f16x8 bk = *(const f16x8*)(kdp + (16*(sct0+j) + l15)*272 + ks*64 + quad*16);
          sacc[j] = MFMA16(aq, bk, sacc[j]);
        }
      }
    }
  }

  // scores -> LDS (f32), causal softmax, attn probs (fp16) -> atn
  RAW_BARRIER();
  {
    const int srt = wid >> 1, sct0 = (wid & 1) * 2;
    #pragma unroll
    for (int j = 0; j < 2; ++j)
      #pragma unroll
      for (int rg = 0; rg < 4; ++rg)
        *(float*)(scb + (16*srt + quad*4 + rg)*272 + (16*(sct0+j) + l15)*4) = sacc[j][rg];
  }
  RAW_BARRIER();
  {
    const int row = tid >> 3, i = tid & 7;   // 8 threads per row, 8 cols each
    f32x4 s0 = *(const f32x4*)(scb + row*272 + 32*i);
    f32x4 s1 = *(const f32x4*)(scb + row*272 + 32*i + 16);
    float s[8] = { s0[0],s0[1],s0[2],s0[3], s1[0],s1[1],s1[2],s1[3] };
    float m = -3.0e38f;
    #pragma unroll
    for (int j = 0; j < 8; ++j) if (8*i + j <= row) m = fmaxf(m, s[j]);
    m = fmaxf(m, __shfl_xor(m, 1));
    m = fmaxf(m, __shfl_xor(m, 2));
    m = fmaxf(m, __shfl_xor(m, 4));
    float e[8]; float sum = 0.f;
    #pragma unroll
    for (int j = 0; j < 8; ++j) {
      e[j] = (8*i + j <= row) ? __expf(s[j] - m) : 0.f;   // NEG_BIG mask == exact zero
      sum += e[j];
    }
    sum += __shfl_xor(sum, 1);
    sum += __shfl_xor(sum, 2);
    sum += __shfl_xor(sum, 4);
    const float inv = 1.0f / sum;
    union { _Float16 h[8]; uint4 u; } o;
    #pragma unroll
    for (int j = 0; j < 8; ++j) o.h[j] = (_Float16)(e[j] * inv);
    *(uint4*)(atn + row*144 + 16*i) = o.u;
  }

  // V projection: wave w owns v[:, 64w..64w+63]; reads persistent tstp, no barriers.
  f32x4 vacc[4][4] = {};
  {
    const _Float16* const fwv = Fv + (size_t)(wid * 4) * 8192 + (size_t)lane * 8;
    PROJ16(fwv, tstp, vacc);
  }

  // out = attn @ v, computed transposed (D[m=d][n=t]) so stores pack 4 consecutive d.
  RAW_BARRIER();   // softmax scb reads + atn writes done before vdp overwrite / PV reads
  char* const vd = vdp + wid * 4352;   // wave-private vT dump [32][68] f16 stride 136
  #pragma unroll
  for (int h = 0; h < 2; ++h) {
    #pragma unroll
    for (int c = 0; c < 2; ++c) {
      const int ct = 2*h + c;
      #pragma unroll
      for (int rt = 0; rt < 4; ++rt)
        #pragma unroll
        for (int rg = 0; rg < 4; ++rg)
          *(_Float16*)(vd + (16*c + l15)*136 + (16*rt + quad*4 + rg)*2)
              = (_Float16)vacc[rt][ct][rg];
    }
    f32x4 oacc[2][4] = {};
    #pragma unroll
    for (int ks = 0; ks < 2; ++ks) {
      f16x8 av[2];
      #pragma unroll
      for (int mt = 0; mt < 2; ++mt)
        av[mt] = *(const f16x8*)(vd + (16*mt + l15)*136 + ks*64 + quad*16);
      #pragma unroll
      for (int nt = 0; nt < 4; ++nt) {
        f16x8 ba = *(const f16x8*)(atn + (16*nt + l15)*144 + ks*64 + quad*16);
        #pragma unroll
        for (int mt = 0; mt < 2; ++mt)
          oacc[mt][nt] = MFMA16(av[mt], ba, oacc[mt][nt]);
      }
    }
    #pragma unroll
    for (int mt = 0; mt < 2; ++mt)
      #pragma unroll
      for (int nt = 0; nt < 4; ++nt) {
        const int d0 = 64*wid + 32*h + 16*mt + quad*4;
        const int tq = 16*nt + l15;
        union { _Float16 h4[4]; uint2 u; } o;
        #pragma unroll
        for (int rg = 0; rg < 4; ++rg) o.h4[rg] = (_Float16)oacc[mt][nt][rg];
        *(uint2*)(outp + scrbase + (size_t)tq * DD + d0) = o.u;   // fp16 scratch
      }
  }
}

// ---- ff = relu(out @ lin_w^T + b); y = 0.5*(ff+out) + (x+pos), fp32 output ----
// Scratch out-tile staged ONCE into 64KB swizzled LDS; lin_w fragments direct
// from L2 with 1-deep register prefetch; 2 blocks/CU guaranteed (VGPR<=128).
__global__ __launch_bounds__(512, 4) void ff_final(
    const _Float16* __restrict__ outp, const float* __restrict__ x,
    const float* __restrict__ pos, const _Float16* __restrict__ lwF,
    const float* __restrict__ lb, float* __restrict__ y)
{
  __shared__ char smem[65536];   // out tile [64] rows x 1024 B, XOR-swizzled

  const int n = blockIdx.x;
  const int tid = threadIdx.x;
  const int wid = tid >> 6, lane = tid & 63, quad = lane >> 4, l15 = lane & 15;
  const size_t scrbase = (size_t)n * 65536 + 32768;

  // stage scratch -> LDS (fully coalesced: 64B contiguous per row-group)
  {
    const int row = tid >> 3, si = tid & 7;
    const _Float16* sr = outp + scrbase + (size_t)row * DD;
    char* const dst = smem + row * 1024;
    const int swz = (row & 7) << 4;
    #pragma unroll
    for (int kb = 0; kb < 16; ++kb)
      *(unsigned long long*)(dst + ((kb * 64 + si * 8) ^ swz)) =
          *(const unsigned long long*)(sr + kb * 32 + 4 * si);
  }

  const int rswz = (l15 & 7) << 4;
  const _Float16* const fA = lwF + (size_t)(wid * 4) * 8192 + (size_t)lane * 8;

  // weight prologue issued BEFORE the barrier: loads fly during the LDS drain
  f16x8 wA_[4], wB_[4];
  LDW4(wA_, fA, 0); LDW4(wB_, fA, 1);
  RAW_BARRIER();   // lgkm-only: ds_writes done, weight loads stay in flight

  f32x4 acc[4][4] = {};            // ffT [64 e of this wave][64 t]
  // 1-deep pipelined loop: consume cur, refill with kb+2
  #define FF_STEP(WC, KB) do { \
      f16x8 bo0 = *(const f16x8*)(smem + (l15) * 1024 + ((((KB) * 64) + quad * 16) ^ rswz)); \
      f16x8 bo1 = *(const f16x8*)(smem + (16 + l15) * 1024 + ((((KB) * 64) + quad * 16) ^ rswz)); \
      f16x8 bo2 = *(const f16x8*)(smem + (32 + l15) * 1024 + ((((KB) * 64) + quad * 16) ^ rswz)); \
      f16x8 bo3 = *(const f16x8*)(smem + (48 + l15) * 1024 + ((((KB) * 64) + quad * 16) ^ rswz)); \
      _Pragma("unroll") \
      for (int mt_ = 0; mt_ < 4; ++mt_) { \
        acc[mt_][0] = MFMA16(WC[mt_], bo0, acc[mt_][0]); \
        acc[mt_][1] = MFMA16(WC[mt_], bo1, acc[mt_][1]); \
        acc[mt_][2] = MFMA16(WC[mt_], bo2, acc[mt_][2]); \
        acc[mt_][3] = MFMA16(WC[mt_], bo3, acc[mt_][3]); \
      } \
      if ((KB) + 2 < 16) LDW4(WC, fA, (KB) + 2); \
    } while (0)
  FF_STEP(wA_, 0);  FF_STEP(wB_, 1);
  FF_STEP(wA_, 2);  FF_STEP(wB_, 3);
  FF_STEP(wA_, 4);  FF_STEP(wB_, 5);
  FF_STEP(wA_, 6);  FF_STEP(wB_, 7);
  FF_STEP(wA_, 8);  FF_STEP(wB_, 9);
  FF_STEP(wA_, 10); FF_STEP(wB_, 11);
  FF_STEP(wA_, 12); FF_STEP(wB_, 13);
  FF_STEP(wA_, 14); FF_STEP(wB_, 15);
  #undef FF_STEP

  // epilogue: out-values from LDS; fp32 writes (clobber dead global scratch)
  #pragma unroll
  for (int mt = 0; mt < 4; ++mt) {
    const int e0 = wid*64 + 16*mt + quad*4;
    f32x4 bias = *(const f32x4*)(lb + e0);
    #pragma unroll
    for (int nt = 0; nt < 4; ++nt) {
      const int tq = 16*nt + l15;
      const size_t base = ((size_t)n * TT + tq) * DD + e0;
      union { _Float16 h4[4]; unsigned long long u; } ov;
      ov.u = *(const unsigned long long*)(smem + tq * 1024 + ((2 * e0) ^ rswz));
      f32x4 xv = *(const f32x4*)(x + ((size_t)tq * NN + n) * DD + e0);
      f32x4 pv = *(const f32x4*)(pos + (size_t)tq * DD + e0);
      f32x4 ro;
      #pragma unroll
      for (int rg = 0; rg < 4; ++rg) {
        float ff = acc[mt][nt][rg] + bias[rg];
        ff = ff > 0.f ? ff : 0.f;
        ro[rg] = 0.5f * (ff + (float)ov.h4[rg]) + xv[rg] + pv[rg];  // exact fp32 temporal
      }
      *(f32x4*)(y + base) = ro;
    }
  }
}

extern "C" void kernel_launch(void* const* d_in, const int* in_sizes, int n_in,
                              void* d_out, int out_size, void* d_ws, size_t ws_size,
                              hipStream_t stream) {
  (void)in_sizes; (void)n_in; (void)out_size; (void)ws_size;
  const float* x   = (const float*)d_in[0];
  const float* pos = (const float*)d_in[1];
  const float* Wq  = (const float*)d_in[2];
  const float* Wk  = (const float*)d_in[3];
  const float* Wv  = (const float*)d_in[4];
  const float* lw  = (const float*)d_in[5];
  const float* lb  = (const float*)d_in[6];
  _Float16* wsW = (_Float16*)d_ws;   // 4 * 262144 fp16 = 2 MB, fragment-major

  prep_weights<<<512, 256, 0, stream>>>(Wq, Wk, Wv, lw, wsW);
  attn_fused<<<2048, 512, 0, stream>>>(x, pos, wsW, (_Float16*)d_out);
  ff_final<<<2048, 512, 0, stream>>>((const _Float16*)d_out, x, pos,
                                     wsW + 786432, lb, (float*)d_out);
}